// Round 6
// baseline (105.021 us; speedup 1.0000x reference)
//
#include <hip/hip_runtime.h>

// DIAGNOSTIC ROUND: gather phase executed TWICE per dispatch (acc * 0.5 at the end,
// output unchanged; memory clobber between passes defeats load-CSE). Purpose: push the
// kernel above the harness's 44us poison fills so rocprof top-5 reveals its duration,
// FETCH_SIZE, VALUBusy, OccupancyPercent. Warm pass removed (round-5: pure +6.8us cost).

#define D 128
#define MAXL 64

__device__ __forceinline__ int lower_bound_serial(const int* __restrict__ s, int n, int v) {
    int lo = 0, hi = n;
    while (lo < hi) {
        int mid = (lo + hi) >> 1;
        if (s[mid] < v) lo = mid + 1; else hi = mid;
    }
    return lo;
}

// Wave-parallel lower_bound over n==8192 (=64*128): 3 dependent loads. Wave-uniform result.
__device__ __forceinline__ int wave_lower_bound_8192(const int* __restrict__ s, int v, int lane) {
    int x1 = s[lane << 7];                    // 64 probes, stride 128
    unsigned long long m1 = __ballot(x1 < v);
    int c1 = __popcll(m1);
    if (c1 == 0) return 0;
    const int lo = ((c1 - 1) << 7) + 1;
    int x2 = s[lo + (lane << 1)];             // 64 probes, stride 2
    unsigned long long m2 = __ballot(x2 < v);
    int c2 = __popcll(m2);
    if (c2 == 64) return lo + 127;
    if (c2 == 0)  return lo;
    const int a = lo + (c2 << 1) - 1;         // 1 scalar probe resolves
    return (s[a] < v) ? a + 1 : a;
}

__global__ __launch_bounds__(256, 8) void seg_embed_sum_kernel(
    const int* __restrict__ tokens,   // [B, T]
    const int* __restrict__ segs,     // [B, T], sorted per row
    const float* __restrict__ table,  // [VOCAB, D]
    float* __restrict__ out,          // [B, MAXL, D]
    int T) {
    const int seg   = blockIdx.x;
    const int b     = blockIdx.y;
    const int tid   = threadIdx.x;
    const int group = tid >> 5;       // 0..7
    const int lane  = tid & 31;

    const int* srow = segs + (size_t)b * T;

    __shared__ int sbounds[2];
    if (T == 8192) {
        const int wave = tid >> 6;
        const int wl   = tid & 63;
        const int lb = wave_lower_bound_8192(srow, seg + (wave & 1), wl);
        if (wl == 0) sbounds[wave & 1] = lb;
    } else {
        if (tid < 2) sbounds[tid] = lower_bound_serial(srow, T, seg + tid);
    }
    __syncthreads();

    const int start = sbounds[0];
    const int end   = sbounds[1];
    const int count = end - start;

    const int* trow = tokens + (size_t)b * T + start;
    const char* tb  = (const char*)table;               // 32-bit voffset addressing
    const uint32_t lo16 = (uint32_t)(lane << 4);

    const int per    = (count + 7) >> 3;
    const int gstart = group * per;
    const int gend   = min(count, gstart + per);

    float4 acc0 = make_float4(0.f, 0.f, 0.f, 0.f);
    float4 acc1 = make_float4(0.f, 0.f, 0.f, 0.f);

    for (int pass = 0; pass < 2; ++pass) {
        for (int base = gstart; base < gend; base += 32) {
            const int n = min(32, gend - base);
            int tok = 0;
            if (lane < n) tok = trow[base + lane];          // coalesced id load
            int j = 0;
            for (; j + 8 <= n; j += 8) {                    // 8 independent 512B row-gathers in flight
                const uint32_t o0 = (uint32_t)__shfl(tok, j,     32) * 512u + lo16;
                const uint32_t o1 = (uint32_t)__shfl(tok, j + 1, 32) * 512u + lo16;
                const uint32_t o2 = (uint32_t)__shfl(tok, j + 2, 32) * 512u + lo16;
                const uint32_t o3 = (uint32_t)__shfl(tok, j + 3, 32) * 512u + lo16;
                const uint32_t o4 = (uint32_t)__shfl(tok, j + 4, 32) * 512u + lo16;
                const uint32_t o5 = (uint32_t)__shfl(tok, j + 5, 32) * 512u + lo16;
                const uint32_t o6 = (uint32_t)__shfl(tok, j + 6, 32) * 512u + lo16;
                const uint32_t o7 = (uint32_t)__shfl(tok, j + 7, 32) * 512u + lo16;
                const float4 v0 = *reinterpret_cast<const float4*>(tb + o0);
                const float4 v1 = *reinterpret_cast<const float4*>(tb + o1);
                const float4 v2 = *reinterpret_cast<const float4*>(tb + o2);
                const float4 v3 = *reinterpret_cast<const float4*>(tb + o3);
                const float4 v4 = *reinterpret_cast<const float4*>(tb + o4);
                const float4 v5 = *reinterpret_cast<const float4*>(tb + o5);
                const float4 v6 = *reinterpret_cast<const float4*>(tb + o6);
                const float4 v7 = *reinterpret_cast<const float4*>(tb + o7);
                acc0.x += v0.x; acc0.y += v0.y; acc0.z += v0.z; acc0.w += v0.w;
                acc1.x += v1.x; acc1.y += v1.y; acc1.z += v1.z; acc1.w += v1.w;
                acc0.x += v2.x; acc0.y += v2.y; acc0.z += v2.z; acc0.w += v2.w;
                acc1.x += v3.x; acc1.y += v3.y; acc1.z += v3.z; acc1.w += v3.w;
                acc0.x += v4.x; acc0.y += v4.y; acc0.z += v4.z; acc0.w += v4.w;
                acc1.x += v5.x; acc1.y += v5.y; acc1.z += v5.z; acc1.w += v5.w;
                acc0.x += v6.x; acc0.y += v6.y; acc0.z += v6.z; acc0.w += v6.w;
                acc1.x += v7.x; acc1.y += v7.y; acc1.z += v7.z; acc1.w += v7.w;
            }
            for (; j < n; ++j) {
                const uint32_t o = (uint32_t)__shfl(tok, j, 32) * 512u + lo16;
                const float4 v = *reinterpret_cast<const float4*>(tb + o);
                acc0.x += v.x; acc0.y += v.y; acc0.z += v.z; acc0.w += v.w;
            }
        }
        // prevent CSE of second-pass loads against the first pass
        asm volatile("" ::: "memory");
    }
    acc0.x += acc1.x; acc0.y += acc1.y; acc0.z += acc1.z; acc0.w += acc1.w;
    // both passes summed the same data -> halve to restore the true sum
    acc0.x *= 0.5f; acc0.y *= 0.5f; acc0.z *= 0.5f; acc0.w *= 0.5f;

    __shared__ float red[8][D];
    *reinterpret_cast<float4*>(&red[group][lane * 4]) = acc0;
    __syncthreads();

    if (tid < 32) {
        float4 s = make_float4(0.f, 0.f, 0.f, 0.f);
        #pragma unroll
        for (int g = 0; g < 8; ++g) {
            const float4 v = *reinterpret_cast<const float4*>(&red[g][tid * 4]);
            s.x += v.x; s.y += v.y; s.z += v.z; s.w += v.w;
        }
        *reinterpret_cast<float4*>(out + ((size_t)b * MAXL + seg) * D + tid * 4) = s;
    }
}

extern "C" void kernel_launch(void* const* d_in, const int* in_sizes, int n_in,
                              void* d_out, int out_size, void* d_ws, size_t ws_size,
                              hipStream_t stream) {
    const int* tokens  = (const int*)d_in[0];     // paragraph_variable [B,T] int32
    const int* segs    = (const int*)d_in[1];     // segment_ids [B,T] int32 (sorted per row)
    const float* table = (const float*)d_in[3];   // embedding_table [VOCAB, D] f32
    float* out         = (float*)d_out;           // [B, MAXL, D] f32

    const int B = out_size / (MAXL * D);          // 32
    const int T = in_sizes[0] / B;                // 8192

    dim3 grid(MAXL, B);                           // 2048 blocks = 8/CU * 256 CU
    seg_embed_sum_kernel<<<grid, 256, 0, stream>>>(tokens, segs, table, out, T);
}

// Round 7
// 89.941 us; speedup vs baseline: 1.1677x; 1.1677x over previous
//
#include <hip/hip_runtime.h>

// ImpSentenceModel: emb = table[tokens]; out[b,seg,:] = sum over tokens with segment_ids==seg.
// segment_ids sorted per row -> each (b,seg) is a contiguous token range [start,end).
// One block per (b,seg): wave-parallel 3-probe lower_bound, 8x 32-lane groups gather+sum
// contiguous stripes with 8-deep load ILP (32-bit voffset addressing), LDS-reduce, one write.
//
// Measured decomposition (rounds 2/5/6): gather pass = 15.5 us (128 MB random 512B rows
// ~ 8.25 TB/s effective through L2/L3 -- above streaming-HBM achievable, i.e. at the
// random-access path limit); kernel total ~18-20 us; remaining ~70 us of dur_us is the
// harness's 268 MB poison fill (44 us @ 76% HBM peak) + input restores. L3 pre-warm
// (round 5) was pure overhead; fp16 side-table nets ~0 (per-call conversion cost).

#define D 128
#define MAXL 64

__device__ __forceinline__ int lower_bound_serial(const int* __restrict__ s, int n, int v) {
    int lo = 0, hi = n;
    while (lo < hi) {
        int mid = (lo + hi) >> 1;
        if (s[mid] < v) lo = mid + 1; else hi = mid;
    }
    return lo;
}

// Wave-parallel lower_bound over n==8192 (=64*128): 3 dependent loads. Wave-uniform result.
__device__ __forceinline__ int wave_lower_bound_8192(const int* __restrict__ s, int v, int lane) {
    int x1 = s[lane << 7];                    // 64 probes, stride 128
    unsigned long long m1 = __ballot(x1 < v);
    int c1 = __popcll(m1);
    if (c1 == 0) return 0;
    const int lo = ((c1 - 1) << 7) + 1;
    int x2 = s[lo + (lane << 1)];             // 64 probes, stride 2
    unsigned long long m2 = __ballot(x2 < v);
    int c2 = __popcll(m2);
    if (c2 == 64) return lo + 127;
    if (c2 == 0)  return lo;
    const int a = lo + (c2 << 1) - 1;         // 1 scalar probe resolves
    return (s[a] < v) ? a + 1 : a;
}

__global__ __launch_bounds__(256, 8) void seg_embed_sum_kernel(
    const int* __restrict__ tokens,   // [B, T]
    const int* __restrict__ segs,     // [B, T], sorted per row
    const float* __restrict__ table,  // [VOCAB, D]
    float* __restrict__ out,          // [B, MAXL, D]
    int T) {
    const int seg   = blockIdx.x;
    const int b     = blockIdx.y;
    const int tid   = threadIdx.x;
    const int group = tid >> 5;       // 0..7
    const int lane  = tid & 31;

    const int* srow = segs + (size_t)b * T;

    __shared__ int sbounds[2];
    if (T == 8192) {
        const int wave = tid >> 6;
        const int wl   = tid & 63;
        const int lb = wave_lower_bound_8192(srow, seg + (wave & 1), wl);
        if (wl == 0) sbounds[wave & 1] = lb;
    } else {
        if (tid < 2) sbounds[tid] = lower_bound_serial(srow, T, seg + tid);
    }
    __syncthreads();

    const int start = sbounds[0];
    const int end   = sbounds[1];
    const int count = end - start;

    const int* trow = tokens + (size_t)b * T + start;
    const char* tb  = (const char*)table;               // 32-bit voffset addressing
    const uint32_t lo16 = (uint32_t)(lane << 4);

    const int per    = (count + 7) >> 3;
    const int gstart = group * per;
    const int gend   = min(count, gstart + per);

    float4 acc0 = make_float4(0.f, 0.f, 0.f, 0.f);
    float4 acc1 = make_float4(0.f, 0.f, 0.f, 0.f);

    for (int base = gstart; base < gend; base += 32) {
        const int n = min(32, gend - base);
        int tok = 0;
        if (lane < n) tok = trow[base + lane];          // coalesced id load
        int j = 0;
        for (; j + 8 <= n; j += 8) {                    // 8 independent 512B row-gathers in flight
            const uint32_t o0 = (uint32_t)__shfl(tok, j,     32) * 512u + lo16;
            const uint32_t o1 = (uint32_t)__shfl(tok, j + 1, 32) * 512u + lo16;
            const uint32_t o2 = (uint32_t)__shfl(tok, j + 2, 32) * 512u + lo16;
            const uint32_t o3 = (uint32_t)__shfl(tok, j + 3, 32) * 512u + lo16;
            const uint32_t o4 = (uint32_t)__shfl(tok, j + 4, 32) * 512u + lo16;
            const uint32_t o5 = (uint32_t)__shfl(tok, j + 5, 32) * 512u + lo16;
            const uint32_t o6 = (uint32_t)__shfl(tok, j + 6, 32) * 512u + lo16;
            const uint32_t o7 = (uint32_t)__shfl(tok, j + 7, 32) * 512u + lo16;
            const float4 v0 = *reinterpret_cast<const float4*>(tb + o0);
            const float4 v1 = *reinterpret_cast<const float4*>(tb + o1);
            const float4 v2 = *reinterpret_cast<const float4*>(tb + o2);
            const float4 v3 = *reinterpret_cast<const float4*>(tb + o3);
            const float4 v4 = *reinterpret_cast<const float4*>(tb + o4);
            const float4 v5 = *reinterpret_cast<const float4*>(tb + o5);
            const float4 v6 = *reinterpret_cast<const float4*>(tb + o6);
            const float4 v7 = *reinterpret_cast<const float4*>(tb + o7);
            acc0.x += v0.x; acc0.y += v0.y; acc0.z += v0.z; acc0.w += v0.w;
            acc1.x += v1.x; acc1.y += v1.y; acc1.z += v1.z; acc1.w += v1.w;
            acc0.x += v2.x; acc0.y += v2.y; acc0.z += v2.z; acc0.w += v2.w;
            acc1.x += v3.x; acc1.y += v3.y; acc1.z += v3.z; acc1.w += v3.w;
            acc0.x += v4.x; acc0.y += v4.y; acc0.z += v4.z; acc0.w += v4.w;
            acc1.x += v5.x; acc1.y += v5.y; acc1.z += v5.z; acc1.w += v5.w;
            acc0.x += v6.x; acc0.y += v6.y; acc0.z += v6.z; acc0.w += v6.w;
            acc1.x += v7.x; acc1.y += v7.y; acc1.z += v7.z; acc1.w += v7.w;
        }
        for (; j < n; ++j) {
            const uint32_t o = (uint32_t)__shfl(tok, j, 32) * 512u + lo16;
            const float4 v = *reinterpret_cast<const float4*>(tb + o);
            acc0.x += v.x; acc0.y += v.y; acc0.z += v.z; acc0.w += v.w;
        }
    }
    acc0.x += acc1.x; acc0.y += acc1.y; acc0.z += acc1.z; acc0.w += acc1.w;

    __shared__ float red[8][D];
    *reinterpret_cast<float4*>(&red[group][lane * 4]) = acc0;
    __syncthreads();

    if (tid < 32) {
        float4 s = make_float4(0.f, 0.f, 0.f, 0.f);
        #pragma unroll
        for (int g = 0; g < 8; ++g) {
            const float4 v = *reinterpret_cast<const float4*>(&red[g][tid * 4]);
            s.x += v.x; s.y += v.y; s.z += v.z; s.w += v.w;
        }
        // exactly-once write; empty segments write zeros (also clears 0xAA poison)
        *reinterpret_cast<float4*>(out + ((size_t)b * MAXL + seg) * D + tid * 4) = s;
    }
}

extern "C" void kernel_launch(void* const* d_in, const int* in_sizes, int n_in,
                              void* d_out, int out_size, void* d_ws, size_t ws_size,
                              hipStream_t stream) {
    const int* tokens  = (const int*)d_in[0];     // paragraph_variable [B,T] int32
    const int* segs    = (const int*)d_in[1];     // segment_ids [B,T] int32 (sorted per row)
    const float* table = (const float*)d_in[3];   // embedding_table [VOCAB, D] f32
    float* out         = (float*)d_out;           // [B, MAXL, D] f32

    const int B = out_size / (MAXL * D);          // 32
    const int T = in_sizes[0] / B;                // 8192

    dim3 grid(MAXL, B);                           // 2048 blocks = 8/CU * 256 CU
    seg_embed_sum_kernel<<<grid, 256, 0, stream>>>(tokens, segs, table, out, T);
}